// Round 2
// baseline (102.339 us; speedup 1.0000x reference)
//
#include <hip/hip_runtime.h>
#include <math.h>

// Problem constants (from reference): keypoints [B,3,M] f32, pc [B,3,N] f32.
#define BATCH 4
#define M 1024
#define N 32768
#define NSPLIT 128                 // pc chunks per batch
#define CHUNK (N / NSPLIT)         // 256 points staged in LDS per block
#define KPT 4                      // keypoints per thread (256 thr * 4 = 1024 = M)
#define TPB 256

// ws layout: [B*M] uint (float bits of min squared distance, clamped >= 0)
//            + [1] uint done-counter  (total 16 KB + 4 B)
__global__ void p2p_init(unsigned* __restrict__ ws) {
    int i = blockIdx.x * blockDim.x + threadIdx.x;
    if (i < BATCH * M) ws[i] = 0x7F800000u;      // +inf
    else if (i == BATCH * M) ws[i] = 0u;         // ticket counter
}

__global__ __launch_bounds__(TPB) void p2p_main(
        const float* __restrict__ kp, const float* __restrict__ pc,
        unsigned* __restrict__ ws, float* __restrict__ out) {
    __shared__ __align__(16) float px[CHUNK];
    __shared__ __align__(16) float py[CHUNK];
    __shared__ __align__(16) float pz[CHUNK];
    __shared__ __align__(16) float pw[CHUNK];    // -0.5 * ||p||^2
    __shared__ float sbuf[TPB / 64];
    __shared__ int lastflag;

    const int b = blockIdx.x / NSPLIT;
    const int c = blockIdx.x % NSPLIT;
    const int t = threadIdx.x;

    // Stage one pc chunk into LDS (coalesced), precompute -||p||^2/2.
    const float* pcb = pc + (size_t)b * 3 * N + c * CHUNK;
    {
        float x = pcb[t], y = pcb[N + t], z = pcb[2 * N + t];
        px[t] = x; py[t] = y; pz[t] = z;
        pw[t] = -0.5f * fmaf(x, x, fmaf(y, y, z * z));
    }

    // Each thread owns KPT keypoints in registers (coalesced loads).
    const float* kpb = kp + (size_t)b * 3 * M;
    float kx[KPT], ky[KPT], kz[KPT], k2[KPT], mq[KPT];
#pragma unroll
    for (int k = 0; k < KPT; ++k) {
        int m = t + k * TPB;
        kx[k] = kpb[m];
        ky[k] = kpb[M + m];
        kz[k] = kpb[2 * M + m];
        k2[k] = fmaf(kx[k], kx[k], fmaf(ky[k], ky[k], kz[k] * kz[k]));
        mq[k] = -INFINITY;
    }
    __syncthreads();

    // Hot loop: min_p ||k-p||^2 = k2 - 2*max_p(k.p - ||p||^2/2).
    // Per pair: 3 fma + shared max -> 48 fma + 8 max3 per iter (was 112 VALU).
#pragma unroll 1
    for (int j = 0; j < CHUNK; j += 4) {
        float4 vx = *(const float4*)&px[j];
        float4 vy = *(const float4*)&py[j];
        float4 vz = *(const float4*)&pz[j];
        float4 vw = *(const float4*)&pw[j];
        float X[4] = {vx.x, vx.y, vx.z, vx.w};
        float Y[4] = {vy.x, vy.y, vy.z, vy.w};
        float Z[4] = {vz.x, vz.y, vz.z, vz.w};
        float W[4] = {vw.x, vw.y, vw.z, vw.w};
#pragma unroll
        for (int k = 0; k < KPT; ++k) {
            float q0 = fmaf(kz[k], Z[0], fmaf(ky[k], Y[0], fmaf(kx[k], X[0], W[0])));
            float q1 = fmaf(kz[k], Z[1], fmaf(ky[k], Y[1], fmaf(kx[k], X[1], W[1])));
            float q2 = fmaf(kz[k], Z[2], fmaf(ky[k], Y[2], fmaf(kx[k], X[2], W[2])));
            float q3 = fmaf(kz[k], Z[3], fmaf(ky[k], Y[3], fmaf(kx[k], X[3], W[3])));
            // fminf/fmaxf chains fuse to v_max3_f32 on gfx950
            mq[k] = fmaxf(fmaxf(mq[k], q0), q1);
            mq[k] = fmaxf(fmaxf(mq[k], q2), q3);
        }
    }

    // Epilogue: d2 = k2 - 2*qmax, clamp >= 0 (keeps uint order == float order),
    // order-independent combine across chunk-blocks via atomicMin on bits.
#pragma unroll
    for (int k = 0; k < KPT; ++k) {
        float d2 = fmaxf(fmaf(-2.0f, mq[k], k2[k]), 0.0f);
        atomicMin(&ws[b * M + t + k * TPB], __float_as_uint(d2));
    }

    // Last-block-done final reduction (saves one dispatch + gap).
    __threadfence();
    if (t == 0) {
        unsigned ticket = atomicAdd(&ws[BATCH * M], 1u);
        lastflag = (ticket == (unsigned)(gridDim.x - 1)) ? 1 : 0;
    }
    __syncthreads();
    if (lastflag) {
        float s = 0.f;
#pragma unroll
        for (int i = t; i < BATCH * M; i += TPB) {
            // agent-scope atomic load: bypass L1, see all XCDs' atomicMin results
            unsigned u = __hip_atomic_load(&ws[i], __ATOMIC_RELAXED,
                                           __HIP_MEMORY_SCOPE_AGENT);
            s += sqrtf(__uint_as_float(u));
        }
#pragma unroll
        for (int off = 32; off > 0; off >>= 1) s += __shfl_down(s, off, 64);
        if ((t & 63) == 0) sbuf[t >> 6] = s;
        __syncthreads();
        if (t == 0) {
            float tot = 0.f;
#pragma unroll
            for (int w = 0; w < TPB / 64; ++w) tot += sbuf[w];
            out[0] = tot / (float)(BATCH * M);
        }
    }
}

extern "C" void kernel_launch(void* const* d_in, const int* in_sizes, int n_in,
                              void* d_out, int out_size, void* d_ws, size_t ws_size,
                              hipStream_t stream) {
    const float* kp = (const float*)d_in[0];   // [B,3,M]
    const float* pc = (const float*)d_in[1];   // [B,3,N]
    float* out = (float*)d_out;
    unsigned* ws = (unsigned*)d_ws;

    p2p_init<<<(BATCH * M + 1 + TPB - 1) / TPB, TPB, 0, stream>>>(ws);
    p2p_main<<<BATCH * NSPLIT, TPB, 0, stream>>>(kp, pc, ws, out);
}